// Round 2
// baseline (169.909 us; speedup 1.0000x reference)
//
#include <hip/hip_runtime.h>
#include <hip/hip_bf16.h>

// Shapes hardcoded: b=16, S=512, IN=256, OUT=128, NB=6, Lo=256, actual_seq_len=512
#define LN_EPS 1e-5f

__device__ __forceinline__ float bf2f(unsigned int u16) {
    union { unsigned int i; float f; } v; v.i = (u16 & 0xffffu) << 16; return v.f;
}
__device__ __forceinline__ unsigned short f2bf(float f) {
    __hip_bfloat16 h = __float2bfloat16(f);
    union { __hip_bfloat16 h; unsigned short u; } v; v.h = h; return v.u;
}

// ---------------- K1: Z = LN(x@M^T), R = x@resW^T ----------------
// 512 blocks x 256 thr; block = 16 rows (row = b*512+s); thread c: 0-127 -> Z channel, 128-255 -> R channel
__global__ __launch_bounds__(256) void k1_zr(const float* __restrict__ x,
                                             const float* __restrict__ M,
                                             const float* __restrict__ resW,
                                             const float* __restrict__ gamma,
                                             const float* __restrict__ beta,
                                             float* __restrict__ Z, float* __restrict__ R) {
    __shared__ float xs[16 * 256];      // 16KB; first 8KB reused as zbuf after main loop
    __shared__ float red1[256], red2[256];
    __shared__ float mus[16], rsg[16];
    int t = threadIdx.x;
    int r0 = blockIdx.x * 16;
    #pragma unroll
    for (int q = 0; q < 4; ++q) {
        int lin4 = t + 256 * q;         // float4 units, 1024 total = 16 rows * 64
        *(float4*)(xs + lin4 * 4) = *(const float4*)(x + (size_t)r0 * 256 + lin4 * 4);
    }
    __syncthreads();
    int c = t;
    const float* wrow = (c < 128) ? (M + c * 256) : (resW + (c - 128) * 256);
    float acc[16];
    #pragma unroll
    for (int r = 0; r < 16; ++r) acc[r] = 0.f;
    for (int kq = 0; kq < 256; kq += 8) {
        float4 wa = *(const float4*)(wrow + kq);
        float4 wb = *(const float4*)(wrow + kq + 4);
        #pragma unroll
        for (int r = 0; r < 16; ++r) {
            const float* xr = xs + r * 256 + kq;
            float4 a = *(const float4*)xr;
            float4 b = *(const float4*)(xr + 4);
            acc[r] += wa.x * a.x + wa.y * a.y + wa.z * a.z + wa.w * a.w
                    + wb.x * b.x + wb.y * b.y + wb.z * b.z + wb.w * b.w;
        }
    }
    __syncthreads();                    // xs no longer needed
    float* zbuf = xs;                   // [16][128]
    if (c < 128) {
        #pragma unroll
        for (int r = 0; r < 16; ++r) zbuf[r * 128 + c] = acc[r];
    }
    __syncthreads();
    {
        int row = t >> 4, seg = t & 15;
        float s1 = 0.f, s2 = 0.f;
        #pragma unroll
        for (int q = 0; q < 8; ++q) { float v = zbuf[row * 128 + seg * 8 + q]; s1 += v; s2 += v * v; }
        red1[row * 16 + seg] = s1; red2[row * 16 + seg] = s2;
    }
    __syncthreads();
    if (t < 16) {
        float s1 = 0.f, s2 = 0.f;
        #pragma unroll
        for (int q = 0; q < 16; ++q) { s1 += red1[t * 16 + q]; s2 += red2[t * 16 + q]; }
        float mu = s1 * (1.0f / 128.0f);
        float var = s2 * (1.0f / 128.0f) - mu * mu;
        mus[t] = mu; rsg[t] = rsqrtf(var + LN_EPS);
    }
    __syncthreads();
    if (c < 128) {
        float g = gamma[c];
        float be = beta[c];
        #pragma unroll
        for (int r = 0; r < 16; ++r)
            Z[(size_t)(r0 + r) * 128 + c] = (acc[r] - mus[r]) * rsg[r] * g + be;
    } else {
        int ci = c - 128;
        #pragma unroll
        for (int r = 0; r < 16; ++r)
            R[(size_t)(r0 + r) * 128 + ci] = acc[r];
    }
}

// ---------------- K2: W[s][e] (bf16) = sum_g P[e][g]*cos(2*pi*s/periods[e][g]) ----------------
// grid (32 e-tiles, 16 s-chunks) x 256 thr; thread owns 2 entries (12 g-slots), loops 32 s
__global__ __launch_bounds__(256) void k2_w(const float* __restrict__ P,
                                            const float* __restrict__ periods,
                                            unsigned short* __restrict__ W) {
    int t = threadIdx.x;
    int et = blockIdx.x;                // 0..31: 512 entries each
    int sc = blockIdx.y;                // 0..15: 32 s each
    int e0 = et * 512 + t * 2;
    const float* pp = P + (size_t)e0 * 6;
    float4 pa = *(const float4*)(pp);
    float4 pb = *(const float4*)(pp + 4);
    float4 pc = *(const float4*)(pp + 8);
    float pf[12] = { pa.x, pa.y, pa.z, pa.w, pb.x, pb.y, pb.z, pb.w, pc.x, pc.y, pc.z, pc.w };
    const float* qp = periods + (size_t)e0 * 6;
    float4 qa = *(const float4*)(qp);
    float4 qb = *(const float4*)(qp + 4);
    float4 qc = *(const float4*)(qp + 8);
    float iv[12] = { __builtin_amdgcn_rcpf(qa.x), __builtin_amdgcn_rcpf(qa.y),
                     __builtin_amdgcn_rcpf(qa.z), __builtin_amdgcn_rcpf(qa.w),
                     __builtin_amdgcn_rcpf(qb.x), __builtin_amdgcn_rcpf(qb.y),
                     __builtin_amdgcn_rcpf(qb.z), __builtin_amdgcn_rcpf(qb.w),
                     __builtin_amdgcn_rcpf(qc.x), __builtin_amdgcn_rcpf(qc.y),
                     __builtin_amdgcn_rcpf(qc.z), __builtin_amdgcn_rcpf(qc.w) };
    for (int ss = 0; ss < 32; ++ss) {
        int s = sc * 32 + ss;
        float sf = (float)s;
        float a0 = 0.f, a1 = 0.f;
        #pragma unroll
        for (int g = 0; g < 6; ++g) {
            float r = __builtin_amdgcn_fractf(sf * iv[g]);        // revolutions in [0,1)
            a0 += pf[g] * __builtin_amdgcn_cosf(r);               // v_cos_f32: cos(2*pi*r)
        }
        #pragma unroll
        for (int g = 6; g < 12; ++g) {
            float r = __builtin_amdgcn_fractf(sf * iv[g]);
            a1 += pf[g] * __builtin_amdgcn_cosf(r);
        }
        unsigned int packed = (unsigned int)f2bf(a0) | ((unsigned int)f2bf(a1) << 16);
        *(unsigned int*)(W + (size_t)s * 16384 + e0) = packed;
    }
}

// ---------------- K2b: T[b,s,i] = sum_j Z[b,s,j]*W[s,i,j] ----------------
// 512 blocks (one per s) x 256 thr; W[s] staged in LDS (pad 132), thread: 2 i x 4 b
__global__ __launch_bounds__(256) void k2b_t(const unsigned short* __restrict__ W,
                                             const float* __restrict__ Z,
                                             float* __restrict__ T) {
    __shared__ unsigned short Ws[128 * 132];
    __shared__ float Zs[16 * 128];
    int t = threadIdx.x;
    int s = blockIdx.x;
    const unsigned short* wg = W + (size_t)s * 16384;
    #pragma unroll
    for (int q = 0; q < 8; ++q) {
        int lin = (t + 256 * q) * 8;
        uint4 u = *(const uint4*)(wg + lin);
        int i = lin >> 7, j = lin & 127;
        unsigned short* d = Ws + i * 132 + j;
        uint2 lo; lo.x = u.x; lo.y = u.y;
        uint2 hi; hi.x = u.z; hi.y = u.w;
        *(uint2*)(d) = lo;
        *(uint2*)(d + 4) = hi;
    }
    #pragma unroll
    for (int m = 0; m < 8; ++m) {
        int idx = m * 256 + t;
        int b = idx >> 7, cch = idx & 127;
        Zs[idx] = Z[(size_t)b * 65536 + s * 128 + cch];
    }
    __syncthreads();
    int ig = t & 63, bg = t >> 6;
    float acc[2][4];
    #pragma unroll
    for (int ii = 0; ii < 2; ++ii)
        #pragma unroll
        for (int bb = 0; bb < 4; ++bb) acc[ii][bb] = 0.f;
    for (int j = 0; j < 128; j += 4) {
        float w[2][4];
        #pragma unroll
        for (int ii = 0; ii < 2; ++ii) {
            const unsigned short* wr = Ws + (ig + 64 * ii) * 132 + j;
            uint2 u = *(const uint2*)wr;
            w[ii][0] = bf2f(u.x); w[ii][1] = bf2f(u.x >> 16);
            w[ii][2] = bf2f(u.y); w[ii][3] = bf2f(u.y >> 16);
        }
        #pragma unroll
        for (int bb = 0; bb < 4; ++bb) {
            float4 z = *(const float4*)(Zs + (bg * 4 + bb) * 128 + j);
            #pragma unroll
            for (int ii = 0; ii < 2; ++ii)
                acc[ii][bb] += w[ii][0] * z.x + w[ii][1] * z.y + w[ii][2] * z.z + w[ii][3] * z.w;
        }
    }
    #pragma unroll
    for (int ii = 0; ii < 2; ++ii) {
        int i = ig + 64 * ii;
        #pragma unroll
        for (int bb = 0; bb < 4; ++bb) {
            int b = bg * 4 + bb;
            T[(size_t)b * 65536 + s * 128 + i] = acc[ii][bb];
        }
    }
}

// ---------------- K3: partial[sc][b][o][i] = sum_{s in chunk} T*Linker + R*resL ----------------
// grid (16 b, 8 o-tiles of 32, 4 s-chunks of 128) x 256 thr; thread: 2 o x 8 i (i stride 16)
__global__ __launch_bounds__(256) void k3_part(const float* __restrict__ T,
                                               const float* __restrict__ R,
                                               const float* __restrict__ Linker,
                                               const float* __restrict__ resL,
                                               float* __restrict__ partial) {
    __shared__ float Tl[32 * 128], Rl[32 * 128];
    __shared__ float Ll[32 * 32], rLl[32 * 32];
    int t = threadIdx.x;
    int b = blockIdx.x, ot = blockIdx.y, sc = blockIdx.z;
    int o0 = ot * 32;
    int ig = t & 15, og = t >> 4;
    float acc[2][8];
    #pragma unroll
    for (int off = 0; off < 2; ++off)
        #pragma unroll
        for (int m = 0; m < 8; ++m) acc[off][m] = 0.f;
    for (int sub = 0; sub < 4; ++sub) {
        int s0 = sc * 128 + sub * 32;
        __syncthreads();
        #pragma unroll
        for (int q = 0; q < 4; ++q) {
            int lin4 = t + 256 * q;                    // float4 units, 1024 total
            int row = lin4 >> 5, col = (lin4 & 31) * 4;
            *(float4*)(Tl + row * 128 + col) =
                *(const float4*)(T + (size_t)b * 65536 + (size_t)(s0 + row) * 128 + col);
            *(float4*)(Rl + row * 128 + col) =
                *(const float4*)(R + (size_t)(b * 512 + s0 + row) * 128 + col);
        }
        {
            int ss = t >> 3, oc = (t & 7) * 4;
            *(float4*)(Ll + ss * 32 + oc) =
                *(const float4*)(Linker + (size_t)(s0 + ss) * 256 + o0 + oc);
            *(float4*)(rLl + ss * 32 + oc) =
                *(const float4*)(resL + (size_t)(s0 + ss) * 256 + o0 + oc);
        }
        __syncthreads();
        for (int ss = 0; ss < 32; ++ss) {
            float l0 = Ll[ss * 32 + og * 2], l1 = Ll[ss * 32 + og * 2 + 1];
            float q0 = rLl[ss * 32 + og * 2], q1 = rLl[ss * 32 + og * 2 + 1];
            #pragma unroll
            for (int m = 0; m < 8; ++m) {
                float tv = Tl[ss * 128 + ig + 16 * m];
                float rv = Rl[ss * 128 + ig + 16 * m];
                acc[0][m] += l0 * tv + q0 * rv;
                acc[1][m] += l1 * tv + q1 * rv;
            }
        }
    }
    size_t base = (size_t)sc * 524288 + (size_t)b * 32768;
    #pragma unroll
    for (int off = 0; off < 2; ++off) {
        int o = o0 + og * 2 + off;
        #pragma unroll
        for (int m = 0; m < 8; ++m)
            partial[base + (size_t)o * 128 + ig + 16 * m] = acc[off][m];
    }
}

// ---------------- K4: out(fp32) = sum of 4 partials ----------------
__global__ __launch_bounds__(256) void k4_out(const float* __restrict__ partial,
                                              float* __restrict__ out) {
    int idx4 = (blockIdx.x * 256 + threadIdx.x) * 4;
    float4 a = *(const float4*)(partial + idx4);
    float4 b = *(const float4*)(partial + 524288 + idx4);
    float4 c = *(const float4*)(partial + 2 * 524288 + idx4);
    float4 d = *(const float4*)(partial + 3 * 524288 + idx4);
    float4 o;
    o.x = a.x + b.x + c.x + d.x;
    o.y = a.y + b.y + c.y + d.y;
    o.z = a.z + b.z + c.z + d.z;
    o.w = a.w + b.w + c.w + d.w;
    *(float4*)(out + idx4) = o;
}

extern "C" void kernel_launch(void* const* d_in, const int* in_sizes, int n_in,
                              void* d_out, int out_size, void* d_ws, size_t ws_size,
                              hipStream_t stream) {
    const float* x      = (const float*)d_in[0];
    const float* M      = (const float*)d_in[1];
    const float* P      = (const float*)d_in[2];
    const float* Linker = (const float*)d_in[3];
    const float* gamma  = (const float*)d_in[4];
    const float* beta   = (const float*)d_in[5];
    const float* resW   = (const float*)d_in[6];
    const float* resL   = (const float*)d_in[7];
    const float* periods= (const float*)d_in[8];
    (void)in_sizes; (void)n_in; (void)out_size; (void)ws_size;

    float* ws = (float*)d_ws;
    // ws layout (float offsets):
    //   Z       [0,        1048576)
    //   R       [1048576,  2097152)
    //   T       [2097152,  3145728)
    //   W(bf16) [3145728,  7340032)   16.8 MB; dead after k2b
    //   partial aliases W region      8 MB    (born in k3, after W is consumed)
    float* Z    = ws;
    float* R    = ws + 1048576;
    float* T    = ws + 2097152;
    unsigned short* W = (unsigned short*)(ws + 3145728);
    float* partial    = ws + 3145728;

    k1_zr<<<512, 256, 0, stream>>>(x, M, resW, gamma, beta, Z, R);
    k2_w<<<dim3(32, 16), 256, 0, stream>>>(P, periods, W);
    k2b_t<<<512, 256, 0, stream>>>(W, Z, T);
    k3_part<<<dim3(16, 8, 4), 256, 0, stream>>>(T, R, Linker, resL, partial);
    k4_out<<<512, 256, 0, stream>>>(partial, (float*)d_out);
}

// Round 3
// 119.119 us; speedup vs baseline: 1.4264x; 1.4264x over previous
//
#include <hip/hip_runtime.h>
#include <hip/hip_bf16.h>

// Shapes hardcoded: b=16, S=512, IN=256, OUT=128, NB=6, Lo=256, actual_seq_len=512
#define LN_EPS 1e-5f

typedef __attribute__((ext_vector_type(8))) short short8;   // 8 bf16 = 4 VGPR (MFMA A/B frag)
typedef __attribute__((ext_vector_type(4))) float floatx4;  // MFMA C/D frag

__device__ __forceinline__ float bf2f(unsigned int u16) {
    union { unsigned int i; float f; } v; v.i = (u16 & 0xffffu) << 16; return v.f;
}
__device__ __forceinline__ unsigned short f2bf(float f) {
    __hip_bfloat16 h = __float2bfloat16(f);
    union { __hip_bfloat16 h; unsigned short u; } v; v.h = h; return v.u;
}
__device__ __forceinline__ unsigned int pack2(float a, float b) {
    return (unsigned int)f2bf(a) | ((unsigned int)f2bf(b) << 16);
}

// ---------------- k_prep: bf16 conversions ----------------
// blocks 0..1023: xb (8192x256); 1024..1055: Wcat=[M;resW] (256x256); 1056..1311: LcatT (256x1024)
__global__ __launch_bounds__(256) void k_prep(const float* __restrict__ x,
                                              const float* __restrict__ M,
                                              const float* __restrict__ resW,
                                              const float* __restrict__ Linker,
                                              const float* __restrict__ resL,
                                              unsigned short* __restrict__ xb,
                                              unsigned short* __restrict__ Wcat,
                                              unsigned short* __restrict__ LcatT) {
    int blk = blockIdx.x, t = threadIdx.x;
    if (blk < 1024) {
        int base = blk * 2048 + t * 8;
        float4 a = *(const float4*)(x + base);
        float4 b = *(const float4*)(x + base + 4);
        uint4 o; o.x = pack2(a.x, a.y); o.y = pack2(a.z, a.w);
        o.z = pack2(b.x, b.y); o.w = pack2(b.z, b.w);
        *(uint4*)(xb + base) = o;
    } else if (blk < 1056) {
        int base = (blk - 1024) * 2048 + t * 8;
        int row = base >> 8, col = base & 255;
        const float* src = (row < 128) ? (M + row * 256 + col) : (resW + (row - 128) * 256 + col);
        float4 a = *(const float4*)src;
        float4 b = *(const float4*)(src + 4);
        uint4 o; o.x = pack2(a.x, a.y); o.y = pack2(a.z, a.w);
        o.z = pack2(b.x, b.y); o.w = pack2(b.z, b.w);
        *(uint4*)(Wcat + base) = o;
    } else {
        int o = blk - 1056;  // 0..255
        #pragma unroll
        for (int q = 0; q < 4; ++q) {
            int k = q * 256 + t;
            float v = (k < 512) ? Linker[(size_t)k * 256 + o] : resL[(size_t)(k - 512) * 256 + o];
            LcatT[(size_t)o * 1024 + k] = f2bf(v);
        }
    }
}

// ---------------- k1: ZR = xb @ Wcat^T (MFMA), LN on Z half ----------------
// grid 256 blocks x 256 thr; block = 32 rows; wave w covers cols w*64..w*64+63 (w<2: Z, w>=2: R)
__global__ __launch_bounds__(256) void k1_zr(const unsigned short* __restrict__ xb,
                                             const unsigned short* __restrict__ Wcat,
                                             const float* __restrict__ gamma,
                                             const float* __restrict__ beta,
                                             unsigned short* __restrict__ Z,
                                             unsigned short* __restrict__ TR) {
    __shared__ float buf[32 * 258];          // stride 258: quads land 8 banks apart
    __shared__ float red1[32 * 8], red2[32 * 8];
    __shared__ float mus[32], rsg[32];
    int t = threadIdx.x, w = t >> 6, l = t & 63;
    int lane15 = l & 15, quad = l >> 4;
    int r0 = blockIdx.x * 32;
    floatx4 acc[2][4] = {};
    for (int kk = 0; kk < 256; kk += 32) {
        int k0 = kk + quad * 8;
        short8 a0 = *(const short8*)(xb + (size_t)(r0 + lane15) * 256 + k0);
        short8 a1 = *(const short8*)(xb + (size_t)(r0 + 16 + lane15) * 256 + k0);
        #pragma unroll
        for (int nt = 0; nt < 4; ++nt) {
            int c = w * 64 + nt * 16 + lane15;
            short8 b = *(const short8*)(Wcat + (size_t)c * 256 + k0);
            acc[0][nt] = __builtin_amdgcn_mfma_f32_16x16x32_bf16(a0, b, acc[0][nt], 0, 0, 0);
            acc[1][nt] = __builtin_amdgcn_mfma_f32_16x16x32_bf16(a1, b, acc[1][nt], 0, 0, 0);
        }
    }
    #pragma unroll
    for (int mt = 0; mt < 2; ++mt)
        #pragma unroll
        for (int nt = 0; nt < 4; ++nt)
            #pragma unroll
            for (int r = 0; r < 4; ++r) {
                int ro = mt * 16 + quad * 4 + r;
                int co = w * 64 + nt * 16 + lane15;
                buf[ro * 258 + co] = acc[mt][nt][r];
            }
    __syncthreads();
    {   // LN stats over j = 0..127 (Z half)
        int r = t >> 3, seg = t & 7;
        float s1 = 0.f, s2 = 0.f;
        #pragma unroll
        for (int e = 0; e < 16; ++e) { float v = buf[r * 258 + seg * 16 + e]; s1 += v; s2 += v * v; }
        red1[r * 8 + seg] = s1; red2[r * 8 + seg] = s2;
    }
    __syncthreads();
    if (t < 32) {
        float s1 = 0.f, s2 = 0.f;
        #pragma unroll
        for (int e = 0; e < 8; ++e) { s1 += red1[t * 8 + e]; s2 += red2[t * 8 + e]; }
        float mu = s1 * (1.0f / 128.0f);
        float var = s2 * (1.0f / 128.0f) - mu * mu;
        mus[t] = mu; rsg[t] = rsqrtf(var + LN_EPS);
    }
    __syncthreads();
    {
        int r = t >> 3, c0 = (t & 7) * 16;
        int grow = r0 + r;                    // = b*512 + s
        float mu = mus[r], rs = rsg[r];
        float zv[16], rv[16];
        #pragma unroll
        for (int e = 0; e < 16; ++e) {
            int j = c0 + e;
            zv[e] = (buf[r * 258 + j] - mu) * rs * gamma[j] + beta[j];
            rv[e] = buf[r * 258 + 128 + j];
        }
        uint4 oz0, oz1, or0, or1;
        oz0.x = pack2(zv[0], zv[1]);  oz0.y = pack2(zv[2], zv[3]);
        oz0.z = pack2(zv[4], zv[5]);  oz0.w = pack2(zv[6], zv[7]);
        oz1.x = pack2(zv[8], zv[9]);  oz1.y = pack2(zv[10], zv[11]);
        oz1.z = pack2(zv[12], zv[13]); oz1.w = pack2(zv[14], zv[15]);
        or0.x = pack2(rv[0], rv[1]);  or0.y = pack2(rv[2], rv[3]);
        or0.z = pack2(rv[4], rv[5]);  or0.w = pack2(rv[6], rv[7]);
        or1.x = pack2(rv[8], rv[9]);  or1.y = pack2(rv[10], rv[11]);
        or1.z = pack2(rv[12], rv[13]); or1.w = pack2(rv[14], rv[15]);
        *(uint4*)(Z + (size_t)grow * 128 + c0) = oz0;
        *(uint4*)(Z + (size_t)grow * 128 + c0 + 8) = oz1;
        int b = grow >> 9, s = grow & 511;
        size_t rbase = ((size_t)b * 1024 + 512 + s) * 128 + c0;
        *(uint4*)(TR + rbase) = or0;
        *(uint4*)(TR + rbase + 8) = or1;
    }
}

// ---------------- k2: W[s][i][j] (bf16) = sum_g P[i][j][g]*cos(2*pi*s/periods[i][j][g]) ----------------
__global__ __launch_bounds__(256) void k2_w(const float* __restrict__ P,
                                            const float* __restrict__ periods,
                                            unsigned short* __restrict__ W) {
    int t = threadIdx.x;
    int et = blockIdx.x;                // 0..31
    int sc = blockIdx.y;                // 0..15
    int e0 = et * 512 + t * 2;
    const float* pp = P + (size_t)e0 * 6;
    float4 pa = *(const float4*)(pp);
    float4 pb = *(const float4*)(pp + 4);
    float4 pc = *(const float4*)(pp + 8);
    float pf[12] = { pa.x, pa.y, pa.z, pa.w, pb.x, pb.y, pb.z, pb.w, pc.x, pc.y, pc.z, pc.w };
    const float* qp = periods + (size_t)e0 * 6;
    float4 qa = *(const float4*)(qp);
    float4 qb = *(const float4*)(qp + 4);
    float4 qc = *(const float4*)(qp + 8);
    float iv[12] = { __builtin_amdgcn_rcpf(qa.x), __builtin_amdgcn_rcpf(qa.y),
                     __builtin_amdgcn_rcpf(qa.z), __builtin_amdgcn_rcpf(qa.w),
                     __builtin_amdgcn_rcpf(qb.x), __builtin_amdgcn_rcpf(qb.y),
                     __builtin_amdgcn_rcpf(qb.z), __builtin_amdgcn_rcpf(qb.w),
                     __builtin_amdgcn_rcpf(qc.x), __builtin_amdgcn_rcpf(qc.y),
                     __builtin_amdgcn_rcpf(qc.z), __builtin_amdgcn_rcpf(qc.w) };
    for (int ss = 0; ss < 32; ++ss) {
        int s = sc * 32 + ss;
        float sf = (float)s;
        float a0 = 0.f, a1 = 0.f;
        #pragma unroll
        for (int g = 0; g < 6; ++g) {
            float r = __builtin_amdgcn_fractf(sf * iv[g]);
            a0 += pf[g] * __builtin_amdgcn_cosf(r);
        }
        #pragma unroll
        for (int g = 6; g < 12; ++g) {
            float r = __builtin_amdgcn_fractf(sf * iv[g]);
            a1 += pf[g] * __builtin_amdgcn_cosf(r);
        }
        *(unsigned int*)(W + (size_t)s * 16384 + e0) = pack2(a0, a1);
    }
}

// ---------------- k2b: T[b,s,i] via MFMA; one wave per s ----------------
// A = Z[:,s,:] (16x128), B rows = W[s][i][:] -> C[b][i]; store into TR[b][s][i]
__global__ __launch_bounds__(64) void k2b_t(const unsigned short* __restrict__ W,
                                            const unsigned short* __restrict__ Z,
                                            unsigned short* __restrict__ TR) {
    int l = threadIdx.x, lane15 = l & 15, quad = l >> 4;
    int s = blockIdx.x;
    floatx4 acc[8] = {};
    #pragma unroll
    for (int kk = 0; kk < 4; ++kk) {
        int k0 = kk * 32 + quad * 8;
        short8 a = *(const short8*)(Z + ((size_t)lane15 * 512 + s) * 128 + k0);
        #pragma unroll
        for (int nt = 0; nt < 8; ++nt) {
            short8 b = *(const short8*)(W + (size_t)s * 16384 + (nt * 16 + lane15) * 128 + k0);
            acc[nt] = __builtin_amdgcn_mfma_f32_16x16x32_bf16(a, b, acc[nt], 0, 0, 0);
        }
    }
    #pragma unroll
    for (int nt = 0; nt < 8; ++nt)
        #pragma unroll
        for (int r = 0; r < 4; ++r) {
            int brow = quad * 4 + r;
            int i = nt * 16 + lane15;
            TR[((size_t)brow * 1024 + s) * 128 + i] = f2bf(acc[nt][r]);
        }
}

// ---------------- k3: out[b][o][i] = LcatT(256x1024) @ TR_b(1024x128)^T-style, split-K over 4 waves ----------------
__global__ __launch_bounds__(256) void k3_out(const unsigned short* __restrict__ LcatT,
                                              const unsigned short* __restrict__ TR,
                                              float* __restrict__ out) {
    __shared__ unsigned short bt[4][64 * 40];   // per-wave [i][k] transpose tile, 80B rows (16B-aligned)
    __shared__ float red[4 * 32 * 64];
    int t = threadIdx.x, w = t >> 6, l = t & 63;
    int lane15 = l & 15, quad = l >> 4;
    int b = blockIdx.x, o0 = blockIdx.y * 32, i0 = blockIdx.z * 64;
    const unsigned short* trb = TR + (size_t)b * 1024 * 128;
    unsigned short* myBt = bt[w];
    floatx4 acc[2][4] = {};
    for (int kk = 0; kk < 8; ++kk) {
        int k0 = w * 256 + kk * 32;
        __syncthreads();   // WAR: previous iter's frag reads done before overwrite
        {
            int kr = l & 31, ih = (l >> 5) * 8;
            #pragma unroll
            for (int q = 0; q < 4; ++q) {
                int ic = ih + q * 16;
                uint4 u = *(const uint4*)(trb + (size_t)(k0 + kr) * 128 + i0 + ic);
                const unsigned short* up = (const unsigned short*)&u;
                #pragma unroll
                for (int e = 0; e < 8; ++e) myBt[(ic + e) * 40 + kr] = up[e];
            }
        }
        __syncthreads();   // RAW: staging visible to all lanes
        short8 afr0 = *(const short8*)(LcatT + (size_t)(o0 + lane15) * 1024 + k0 + quad * 8);
        short8 afr1 = *(const short8*)(LcatT + (size_t)(o0 + 16 + lane15) * 1024 + k0 + quad * 8);
        #pragma unroll
        for (int nt = 0; nt < 4; ++nt) {
            short8 bfr = *(const short8*)(myBt + (nt * 16 + lane15) * 40 + quad * 8);
            acc[0][nt] = __builtin_amdgcn_mfma_f32_16x16x32_bf16(afr0, bfr, acc[0][nt], 0, 0, 0);
            acc[1][nt] = __builtin_amdgcn_mfma_f32_16x16x32_bf16(afr1, bfr, acc[1][nt], 0, 0, 0);
        }
    }
    #pragma unroll
    for (int mt = 0; mt < 2; ++mt)
        #pragma unroll
        for (int nt = 0; nt < 4; ++nt)
            #pragma unroll
            for (int r = 0; r < 4; ++r) {
                int ro = mt * 16 + quad * 4 + r;
                int co = nt * 16 + lane15;
                red[(w * 32 + ro) * 64 + co] = acc[mt][nt][r];
            }
    __syncthreads();
    {
        int ro = t >> 3, c0 = (t & 7) * 8;
        float vs[8];
        #pragma unroll
        for (int e = 0; e < 8; ++e) {
            float sum = 0.f;
            #pragma unroll
            for (int ww = 0; ww < 4; ++ww) sum += red[(ww * 32 + ro) * 64 + c0 + e];
            vs[e] = sum;
        }
        float4 o1 = { vs[0], vs[1], vs[2], vs[3] };
        float4 o2 = { vs[4], vs[5], vs[6], vs[7] };
        size_t ob = ((size_t)b * 256 + o0 + ro) * 128 + i0 + c0;
        *(float4*)(out + ob) = o1;
        *(float4*)(out + ob + 4) = o2;
    }
}

extern "C" void kernel_launch(void* const* d_in, const int* in_sizes, int n_in,
                              void* d_out, int out_size, void* d_ws, size_t ws_size,
                              hipStream_t stream) {
    const float* x      = (const float*)d_in[0];
    const float* M      = (const float*)d_in[1];
    const float* P      = (const float*)d_in[2];
    const float* Linker = (const float*)d_in[3];
    const float* gamma  = (const float*)d_in[4];
    const float* beta   = (const float*)d_in[5];
    const float* resW   = (const float*)d_in[6];
    const float* resL   = (const float*)d_in[7];
    const float* periods= (const float*)d_in[8];
    (void)in_sizes; (void)n_in; (void)out_size; (void)ws_size;

    float* ws = (float*)d_ws;
    // ws layout (float offsets):
    //   xb    [0,        1048576)   8192x256 bf16
    //   Wcat  [1048576,  1081344)   256x256 bf16
    //   LcatT [1081344,  1212416)   256x1024 bf16
    //   Z     [1212416,  1736704)   8192x128 bf16  ([b][s][j])
    //   TR    [1736704,  2785280)   16x1024x128 bf16 (k<512: T, k>=512: R)
    //   W     [2785280,  6979584)   512x128x128 bf16
    unsigned short* xb    = (unsigned short*)(ws);
    unsigned short* Wcat  = (unsigned short*)(ws + 1048576);
    unsigned short* LcatT = (unsigned short*)(ws + 1081344);
    unsigned short* Z     = (unsigned short*)(ws + 1212416);
    unsigned short* TR    = (unsigned short*)(ws + 1736704);
    unsigned short* W     = (unsigned short*)(ws + 2785280);

    k_prep<<<1312, 256, 0, stream>>>(x, M, resW, Linker, resL, xb, Wcat, LcatT);
    k2_w<<<dim3(32, 16), 256, 0, stream>>>(P, periods, W);
    k1_zr<<<256, 256, 0, stream>>>(xb, Wcat, gamma, beta, Z, TR);
    k2b_t<<<512, 64, 0, stream>>>(W, Z, TR);
    k3_out<<<dim3(16, 8, 2), 256, 0, stream>>>(LcatT, TR, (float*)d_out);
}